// Round 10
// baseline (1318.951 us; speedup 1.0000x reference)
//
#include <hip/hip_runtime.h>

// ---------------------------------------------------------------------------
// GCN 2-layer forward, dst-partitioned edges + LDS aggregation.
//   N=50000, E=800000, F: 128 -> 128 -> 64.
//   Partition p owns nodes [p*64, p*64+64), P=782.
//   Edge record: rec4 = (src<<16) | bf16(ew);  dl8 = dst & 63.
//   1. memset pcnt;  hist (LDS histogram, block-flush atomics)
//   2. pscan: exclusive scan -> poff/pcur
//   3. pscatter: block LDS histogram -> per-(block,partition) base -> write recs
//   4. deg_p: dis[c] = rsqrt(1 + segsum ew)        (LDS atomics)
//   5. gemm1: H1s = dis_r * (x @ W1)               (4x4 reg tile, bf16)
//   6. gather1_p: LDS agg += ew*H1s[src]; agg1 = relu(dis_c*(agg+H1s[c])+b1)
//   7. gemm2: H2s = dis_r * (agg1 @ W2)            (bf16)
//   8. gather2_p: LDS agg += ew*H2s[src]; out = logsoftmax(dis_c*(agg+H2s[c])+b2)
// ---------------------------------------------------------------------------

#define NP 782            // ceil(50000/64)
#define EPB 16384         // edges per block in hist/pscatter

__device__ __forceinline__ float bflo(uint u) { return __uint_as_float(u << 16); }
__device__ __forceinline__ float bfhi(uint u) { return __uint_as_float(u & 0xffff0000u); }
__device__ __forceinline__ float bfs(unsigned short h) { return __uint_as_float(((uint)h) << 16); }
__device__ __forceinline__ unsigned short f2bf(float f) {
  union { float f; uint u; } v{f};
  return (unsigned short)((v.u + 0x7fff + ((v.u >> 16) & 1)) >> 16);  // RNE
}
__device__ __forceinline__ uint pack2(float a, float b) {
  return (uint)f2bf(a) | ((uint)f2bf(b) << 16);
}

// ---- 1. per-block LDS histogram of dst partitions ----
__global__ void k_hist(const int* __restrict__ col, int* __restrict__ pcnt, int E) {
  __shared__ int h[NP];
  int t = threadIdx.x;
  for (int i = t; i < NP; i += 256) h[i] = 0;
  __syncthreads();
  int e0 = blockIdx.x * EPB;
#pragma unroll 4
  for (int k = 0; k < EPB / 256; ++k) {
    int e = e0 + k * 256 + t;
    if (e < E) atomicAdd(&h[col[e] >> 6], 1);
  }
  __syncthreads();
  for (int i = t; i < NP; i += 256)
    if (h[i]) atomicAdd(&pcnt[i], h[i]);
}

// ---- 2. exclusive scan of pcnt -> poff, pcur ----
__global__ void k_pscan(const int* __restrict__ pcnt, int* __restrict__ poff,
                        int* __restrict__ pcur) {
  __shared__ int s[1024];
  int t = threadIdx.x;
  int v = (t < NP) ? pcnt[t] : 0;
  s[t] = v;
  __syncthreads();
  for (int off = 1; off < 1024; off <<= 1) {
    int add = (t >= off) ? s[t - off] : 0;
    __syncthreads();
    s[t] += add;
    __syncthreads();
  }
  if (t <= NP) {
    int x = s[t] - v;
    poff[t] = x;
    pcur[t] = x;
  }
}

// ---- 3. scatter records into partition regions ----
__global__ void k_pscatter(const int* __restrict__ row, const int* __restrict__ col,
                           const float* __restrict__ ew, int* __restrict__ pcur,
                           uint* __restrict__ rec4, unsigned char* __restrict__ dl8,
                           int E) {
  __shared__ int h[NP];
  __shared__ int bse[NP];
  __shared__ int lc[NP];
  int t = threadIdx.x;
  for (int i = t; i < NP; i += 256) h[i] = 0;
  __syncthreads();
  int e0 = blockIdx.x * EPB;
#pragma unroll 4
  for (int k = 0; k < EPB / 256; ++k) {
    int e = e0 + k * 256 + t;
    if (e < E) atomicAdd(&h[col[e] >> 6], 1);
  }
  __syncthreads();
  for (int i = t; i < NP; i += 256) {
    int c = h[i];
    bse[i] = c ? atomicAdd(&pcur[i], c) : 0;
    lc[i] = 0;
  }
  __syncthreads();
#pragma unroll 4
  for (int k = 0; k < EPB / 256; ++k) {
    int e = e0 + k * 256 + t;
    if (e < E) {
      int c = col[e];
      int p = c >> 6;
      int s = bse[p] + atomicAdd(&lc[p], 1);
      rec4[s] = ((uint)row[e] << 16) | (uint)f2bf(ew[e]);
      dl8[s] = (unsigned char)(c & 63);
    }
  }
}

// ---- 4. dis[c] = rsqrt(1 + sum ew) per partition ----
__global__ void k_deg_p(const int* __restrict__ poff, const uint* __restrict__ rec4,
                        const unsigned char* __restrict__ dl8, float* __restrict__ dis,
                        int n) {
  __shared__ float sd[64];
  int t = threadIdx.x;
  int p = blockIdx.x;
  if (t < 64) sd[t] = 1.0f;
  __syncthreads();
  int jb = poff[p], je = poff[p + 1];
  for (int j = jb + t; j < je; j += 256)
    atomicAdd(&sd[dl8[j]], bflo(rec4[j]));
  __syncthreads();
  int node = p * 64 + t;
  if (t < 64 && node < n) dis[node] = rsqrtf(sd[t]);
}

// ---- 5. H1s = dis_r * (x @ W1), 32 rows/block, 4x4 reg tile, bf16 out ----
#define GPAD 36
__global__ void k_gemm1(const float* __restrict__ x, const float* __restrict__ W,
                        const float* __restrict__ dis, uint* __restrict__ H1b, int n) {
  __shared__ float xs[128 * GPAD];
  int t = threadIdx.x;
  int r0 = blockIdx.x * 32;
  for (int i = t; i < 32 * 128; i += 256) {
    int rr = i >> 7, kk = i & 127;
    float v = (r0 + rr < n) ? x[(size_t)(r0 + rr) * 128 + kk] : 0.0f;
    xs[kk * GPAD + rr] = v;
  }
  __syncthreads();
  int cg = t & 31;
  int rg = t >> 5;
  float acc[4][4] = {};
#pragma unroll 8
  for (int k = 0; k < 128; ++k) {
    float4 wv = *(const float4*)&W[k * 128 + cg * 4];
    float4 xv = *(const float4*)&xs[k * GPAD + rg * 4];
    acc[0][0] = fmaf(xv.x, wv.x, acc[0][0]);
    acc[0][1] = fmaf(xv.x, wv.y, acc[0][1]);
    acc[0][2] = fmaf(xv.x, wv.z, acc[0][2]);
    acc[0][3] = fmaf(xv.x, wv.w, acc[0][3]);
    acc[1][0] = fmaf(xv.y, wv.x, acc[1][0]);
    acc[1][1] = fmaf(xv.y, wv.y, acc[1][1]);
    acc[1][2] = fmaf(xv.y, wv.z, acc[1][2]);
    acc[1][3] = fmaf(xv.y, wv.w, acc[1][3]);
    acc[2][0] = fmaf(xv.z, wv.x, acc[2][0]);
    acc[2][1] = fmaf(xv.z, wv.y, acc[2][1]);
    acc[2][2] = fmaf(xv.z, wv.z, acc[2][2]);
    acc[2][3] = fmaf(xv.z, wv.w, acc[2][3]);
    acc[3][0] = fmaf(xv.w, wv.x, acc[3][0]);
    acc[3][1] = fmaf(xv.w, wv.y, acc[3][1]);
    acc[3][2] = fmaf(xv.w, wv.z, acc[3][2]);
    acc[3][3] = fmaf(xv.w, wv.w, acc[3][3]);
  }
#pragma unroll
  for (int i = 0; i < 4; ++i) {
    int r = r0 + rg * 4 + i;
    if (r < n) {
      float ds = dis[r];
      uint2 o = {pack2(acc[i][0] * ds, acc[i][1] * ds),
                 pack2(acc[i][2] * ds, acc[i][3] * ds)};
      *(uint2*)&H1b[((uint)r << 6) + cg * 2] = o;
    }
  }
}

// ---- 6. partition gather layer 1: LDS float accumulation ----
// sE[d][l] accumulates feat 2l, sO[d][l] feat 2l+1 (bank-conflict-free ds_add).
__global__ void __launch_bounds__(256) k_gather1_p(
    const int* __restrict__ poff, const uint* __restrict__ rec4,
    const unsigned char* __restrict__ dl8, const uint* __restrict__ H1b,
    const float* __restrict__ dis, const float* __restrict__ b1,
    uint* __restrict__ agg1, int n) {
  __shared__ float sE[64 * 64];
  __shared__ float sO[64 * 64];
  int t = threadIdx.x;
  int p = blockIdx.x;
  for (int i = t; i < 4096; i += 256) { sE[i] = 0.0f; sO[i] = 0.0f; }
  __syncthreads();
  int jb = poff[p], je = poff[p + 1];
  int wid = t >> 6, lane = t & 63;
  for (int j = jb + wid * 64; j < je; j += 256) {
    int idx = j + lane;
    bool val = idx < je;
    uint mr = val ? rec4[idx] : 0u;
    int md = val ? (int)dl8[idx] : 0;
    int cnt = je - j;
    cnt = (cnt < 64) ? cnt : 64;
    int sb = 0;
    for (; sb + 8 <= cnt; sb += 8) {
      uint rr[8]; int dd[8];
#pragma unroll
      for (int i = 0; i < 8; ++i) {
        rr[i] = (uint)__shfl((int)mr, sb + i);
        dd[i] = __shfl(md, sb + i);
      }
      uint uu[8];
#pragma unroll
      for (int i = 0; i < 8; ++i)
        uu[i] = H1b[((rr[i] >> 16) << 6) | lane];
#pragma unroll
      for (int i = 0; i < 8; ++i) {
        float wv = bflo(rr[i]);
        atomicAdd(&sE[dd[i] * 64 + lane], wv * bflo(uu[i]));
        atomicAdd(&sO[dd[i] * 64 + lane], wv * bfhi(uu[i]));
      }
    }
    for (; sb < cnt; ++sb) {
      uint r = (uint)__shfl((int)mr, sb);
      int d = __shfl(md, sb);
      uint u = H1b[((r >> 16) << 6) | lane];
      float wv = bflo(r);
      atomicAdd(&sE[d * 64 + lane], wv * bflo(u));
      atomicAdd(&sO[d * 64 + lane], wv * bfhi(u));
    }
  }
  __syncthreads();
  // finalize: agg1 = relu(dis_c*(acc + H1s[c]) + b1), wave handles 16 nodes
  float2 bb = *(const float2*)&b1[lane * 2];
  for (int nl = wid; nl < 64; nl += 4) {
    int node = p * 64 + nl;
    if (node >= n) break;
    float dcs = dis[node];
    uint uc = H1b[((uint)node << 6) | lane];
    float a0 = fmaf(dcs, sE[nl * 64 + lane] + bflo(uc), bb.x);
    float a1 = fmaf(dcs, sO[nl * 64 + lane] + bfhi(uc), bb.y);
    a0 = fmaxf(a0, 0.0f);
    a1 = fmaxf(a1, 0.0f);
    agg1[((uint)node << 6) | lane] = pack2(a0, a1);
  }
}

// ---- 7. H2s = dis_r * (agg1 @ W2), 64 rows/block, 4x4 reg tile ----
#define G2PAD 68
__global__ void k_gemm2(const uint* __restrict__ agg1, const float* __restrict__ W2,
                        const float* __restrict__ dis, unsigned short* __restrict__ H2b,
                        int n) {
  __shared__ float xs[128 * G2PAD];
  int t = threadIdx.x;
  int r0 = blockIdx.x * 64;
  for (int idx = t; idx < 64 * 64; idx += 256) {
    int row = idx >> 6, i = idx & 63;
    uint u = agg1[((uint)(r0 + row) << 6) | i];
    xs[(2 * i) * G2PAD + row]     = bflo(u);
    xs[(2 * i + 1) * G2PAD + row] = bfhi(u);
  }
  __syncthreads();
  int cg = t & 15;
  int rg = t >> 4;
  float acc[4][4] = {};
#pragma unroll 8
  for (int k = 0; k < 128; ++k) {
    float4 wv = *(const float4*)&W2[k * 64 + cg * 4];
    float4 xv = *(const float4*)&xs[k * G2PAD + rg * 4];
    acc[0][0] = fmaf(xv.x, wv.x, acc[0][0]);
    acc[0][1] = fmaf(xv.x, wv.y, acc[0][1]);
    acc[0][2] = fmaf(xv.x, wv.z, acc[0][2]);
    acc[0][3] = fmaf(xv.x, wv.w, acc[0][3]);
    acc[1][0] = fmaf(xv.y, wv.x, acc[1][0]);
    acc[1][1] = fmaf(xv.y, wv.y, acc[1][1]);
    acc[1][2] = fmaf(xv.y, wv.z, acc[1][2]);
    acc[1][3] = fmaf(xv.y, wv.w, acc[1][3]);
    acc[2][0] = fmaf(xv.z, wv.x, acc[2][0]);
    acc[2][1] = fmaf(xv.z, wv.y, acc[2][1]);
    acc[2][2] = fmaf(xv.z, wv.z, acc[2][2]);
    acc[2][3] = fmaf(xv.z, wv.w, acc[2][3]);
    acc[3][0] = fmaf(xv.w, wv.x, acc[3][0]);
    acc[3][1] = fmaf(xv.w, wv.y, acc[3][1]);
    acc[3][2] = fmaf(xv.w, wv.z, acc[3][2]);
    acc[3][3] = fmaf(xv.w, wv.w, acc[3][3]);
  }
#pragma unroll
  for (int i = 0; i < 4; ++i) {
    int r = r0 + rg * 4 + i;
    if (r < n) {
      float ds = dis[r];
      uint2 o = {pack2(acc[i][0] * ds, acc[i][1] * ds),
                 pack2(acc[i][2] * ds, acc[i][3] * ds)};
      *(uint2*)&H2b[((uint)r << 6) + cg * 4] = o;
    }
  }
}

// ---- 8. partition gather layer 2 + log_softmax ----
__global__ void __launch_bounds__(256) k_gather2_p(
    const int* __restrict__ poff, const uint* __restrict__ rec4,
    const unsigned char* __restrict__ dl8, const unsigned short* __restrict__ H2b,
    const float* __restrict__ dis, const float* __restrict__ b2,
    float* __restrict__ out, int n) {
  __shared__ float sA[64 * 64];
  int t = threadIdx.x;
  int p = blockIdx.x;
  for (int i = t; i < 4096; i += 256) sA[i] = 0.0f;
  __syncthreads();
  int jb = poff[p], je = poff[p + 1];
  int wid = t >> 6, lane = t & 63;
  for (int j = jb + wid * 64; j < je; j += 256) {
    int idx = j + lane;
    bool val = idx < je;
    uint mr = val ? rec4[idx] : 0u;
    int md = val ? (int)dl8[idx] : 0;
    int cnt = je - j;
    cnt = (cnt < 64) ? cnt : 64;
    int sb = 0;
    for (; sb + 8 <= cnt; sb += 8) {
      uint rr[8]; int dd[8];
#pragma unroll
      for (int i = 0; i < 8; ++i) {
        rr[i] = (uint)__shfl((int)mr, sb + i);
        dd[i] = __shfl(md, sb + i);
      }
      float hh[8];
#pragma unroll
      for (int i = 0; i < 8; ++i)
        hh[i] = bfs(H2b[((rr[i] >> 16) << 6) | lane]);
#pragma unroll
      for (int i = 0; i < 8; ++i)
        atomicAdd(&sA[dd[i] * 64 + lane], bflo(rr[i]) * hh[i]);
    }
    for (; sb < cnt; ++sb) {
      uint r = (uint)__shfl((int)mr, sb);
      int d = __shfl(md, sb);
      atomicAdd(&sA[d * 64 + lane], bflo(r) * bfs(H2b[((r >> 16) << 6) | lane]));
    }
  }
  __syncthreads();
  // finalize + log_softmax: wave per node, 16 nodes per wave
  float bv = b2[lane];
  for (int nl = wid; nl < 64; nl += 4) {
    int node = p * 64 + nl;
    if (node >= n) break;
    float dcs = dis[node];
    float a = fmaf(dcs, sA[nl * 64 + lane] + bfs(H2b[((uint)node << 6) | lane]), bv);
    float m = a;
#pragma unroll
    for (int sft = 32; sft >= 1; sft >>= 1) m = fmaxf(m, __shfl_xor(m, sft, 64));
    float e = expf(a - m);
    float sum = e;
#pragma unroll
    for (int sft = 32; sft >= 1; sft >>= 1) sum += __shfl_xor(sum, sft, 64);
    out[(size_t)node * 64 + lane] = a - m - logf(sum);
  }
}

extern "C" void kernel_launch(void* const* d_in, const int* in_sizes, int n_in,
                              void* d_out, int out_size, void* d_ws, size_t ws_size,
                              hipStream_t stream) {
  const float* x  = (const float*)d_in[0];
  const int*   ei = (const int*)d_in[1];
  const float* ew = (const float*)d_in[2];
  const float* W1 = (const float*)d_in[3];
  const float* b1 = (const float*)d_in[4];
  const float* W2 = (const float*)d_in[5];
  const float* b2 = (const float*)d_in[6];

  const int n = in_sizes[0] / 128;     // 50000
  const int E = in_sizes[1] / 2;       // 800000
  const int* row = ei;
  const int* col = ei + E;
  float* out = (float*)d_out;

  // workspace layout (~36 MB)
  size_t n_r = (size_t)((n + 255) & ~255);    // 50176
  size_t E_r = (size_t)((E + 255) & ~255);
  char* ws = (char*)d_ws;
  float* dis  = (float*)ws;            ws += n_r * 4;
  int*   pcnt = (int*)ws;              ws += 1024 * 4;
  int*   poff = (int*)ws;              ws += 1024 * 4;
  int*   pcur = (int*)ws;              ws += 1024 * 4;
  uint*  rec4 = (uint*)ws;             ws += E_r * 4;                 // 3.2 MB
  unsigned char* dl8 = (unsigned char*)ws;  ws += E_r;                // 0.8 MB
  uint*  H1b  = (uint*)ws;             ws += n_r * 64 * 4;            // 12.8 MB
  uint*  agg1 = (uint*)ws;             ws += n_r * 64 * 4;            // 12.8 MB
  unsigned short* H2b = (unsigned short*)ws;                          // 6.4 MB

  const int NB = (E + EPB - 1) / EPB;         // 49

  hipMemsetAsync(pcnt, 0, 1024 * sizeof(int), stream);
  k_hist<<<NB, 256, 0, stream>>>(col, pcnt, E);
  k_pscan<<<1, 1024, 0, stream>>>(pcnt, poff, pcur);
  k_pscatter<<<NB, 256, 0, stream>>>(row, col, ew, pcur, rec4, dl8, E);
  k_deg_p<<<NP, 256, 0, stream>>>(poff, rec4, dl8, dis, n);

  k_gemm1<<<(n + 31) / 32, 256, 0, stream>>>(x, W1, dis, H1b, n);
  k_gather1_p<<<NP, 256, 0, stream>>>(poff, rec4, dl8, H1b, dis, b1, agg1, n);
  k_gemm2<<<(n + 63) / 64, 256, 0, stream>>>(agg1, W2, dis, H2b, n);
  k_gather2_p<<<NP, 256, 0, stream>>>(poff, rec4, dl8, H2b, dis, b2, out, n);
}

// Round 11
// 285.607 us; speedup vs baseline: 4.6181x; 4.6181x over previous
//
#include <hip/hip_runtime.h>

// ---------------------------------------------------------------------------
// GCN 2-layer forward: partitioned low-atomic CSR build + per-node wave gathers.
//   N=50000, E=800000, F: 128 -> 128 -> 64.
//   Partition p owns nodes [p*64, p*64+64), NP=782, CAP_P=1216 slots/partition.
//   Edge record: rec = (src<<16) | bf16(ew).
//   1. initcur: pcur[p] = p*CAP_P
//   2. pscatter: block LDS histogram(782) -> global reserve -> write rec+dl8
//   3. sortdeg: per-partition counting sort by node -> sed + nbeg/nend + dis
//   4. gemm1:   H1s = dis_r * (x @ W1)    (4x4 reg tile, bf16 store)
//   5. gather1: agg1 = relu(dis_c*(H1s[c] + sum ew*H1s[src]) + b1)   1 wave/node
//   6. gemm2:   H2s = dis_r * (agg1 @ W2) (bf16)
//   7. gather2: out = logsoftmax(dis_c*(H2s[c] + sum ew*H2s[src]) + b2)
// ---------------------------------------------------------------------------

#define NP 782
#define CAP_P 1216
#define EPB 16384

__device__ __forceinline__ float bflo(uint u) { return __uint_as_float(u << 16); }
__device__ __forceinline__ float bfhi(uint u) { return __uint_as_float(u & 0xffff0000u); }
__device__ __forceinline__ float bfs(unsigned short h) { return __uint_as_float(((uint)h) << 16); }
__device__ __forceinline__ unsigned short f2bf(float f) {
  union { float f; uint u; } v{f};
  return (unsigned short)((v.u + 0x7fff + ((v.u >> 16) & 1)) >> 16);  // RNE
}
__device__ __forceinline__ uint pack2(float a, float b) {
  return (uint)f2bf(a) | ((uint)f2bf(b) << 16);
}

__global__ void k_initcur(int* __restrict__ pcur) {
  int i = blockIdx.x * blockDim.x + threadIdx.x;
  if (i < NP) pcur[i] = i * CAP_P;
}

// ---- 2. partition scatter: 2-pass LDS histogram, per-(block,partition) reserve ----
__global__ void k_pscatter(const int* __restrict__ row, const int* __restrict__ col,
                           const float* __restrict__ ew, int* __restrict__ pcur,
                           uint* __restrict__ rec4, unsigned char* __restrict__ dl8,
                           int E) {
  __shared__ int h[NP];
  __shared__ int bse[NP];
  __shared__ int lc[NP];
  int t = threadIdx.x;
  for (int i = t; i < NP; i += 256) h[i] = 0;
  __syncthreads();
  int e0 = blockIdx.x * EPB;
#pragma unroll 4
  for (int k = 0; k < EPB / 256; ++k) {
    int e = e0 + k * 256 + t;
    if (e < E) atomicAdd(&h[col[e] >> 6], 1);
  }
  __syncthreads();
  for (int i = t; i < NP; i += 256) {
    int c = h[i];
    bse[i] = c ? atomicAdd(&pcur[i], c) : 0;
    lc[i] = 0;
  }
  __syncthreads();
#pragma unroll 4
  for (int k = 0; k < EPB / 256; ++k) {
    int e = e0 + k * 256 + t;
    if (e < E) {
      int c = col[e];
      int p = c >> 6;
      int s = bse[p] + atomicAdd(&lc[p], 1);
      int lim = (p + 1) * CAP_P - 1;
      s = (s < lim) ? s : lim;               // unreachable for this input
      rec4[s] = ((uint)row[e] << 16) | (uint)f2bf(ew[e]);
      dl8[s] = (unsigned char)(c & 63);
    }
  }
}

// ---- 3. per-partition counting sort by node + degrees ----
__global__ void __launch_bounds__(256) k_sortdeg(
    const int* __restrict__ pcur, const uint* __restrict__ rec4,
    const unsigned char* __restrict__ dl8, uint* __restrict__ sed,
    int* __restrict__ nbeg, int* __restrict__ nend, float* __restrict__ dis, int n) {
  __shared__ int h[64];
  __shared__ int lo[64];
  __shared__ int lc[64];
  __shared__ float sd[64];
  int t = threadIdx.x;
  int p = blockIdx.x;
  if (t < 64) { h[t] = 0; lc[t] = 0; sd[t] = 0.0f; }
  __syncthreads();
  int jb = p * CAP_P;
  int cnt = pcur[p] - jb;
  cnt = (cnt < CAP_P) ? cnt : CAP_P;
  for (int j = t; j < cnt; j += 256) {
    int d = dl8[jb + j];
    atomicAdd(&h[d], 1);
    atomicAdd(&sd[d], bflo(rec4[jb + j]));
  }
  __syncthreads();
  if (t < 64) {
    int v = h[t];
    int x = v;
#pragma unroll
    for (int off = 1; off < 64; off <<= 1) {
      int y = __shfl_up(x, off, 64);
      if (t >= off) x += y;
    }
    int excl = x - v;
    lo[t] = excl;
    int node = p * 64 + t;
    if (node < n) {
      nbeg[node] = jb + excl;
      nend[node] = jb + excl + v;
      dis[node] = rsqrtf(1.0f + sd[t]);
    }
  }
  __syncthreads();
  for (int j = t; j < cnt; j += 256) {
    uint r = rec4[jb + j];
    int d = dl8[jb + j];
    int s = jb + lo[d] + atomicAdd(&lc[d], 1);
    sed[s] = r;
  }
}

// ---- 4. H1s = dis_r * (x @ W1), 32 rows/block, 4x4 reg tile, bf16 out ----
#define GPAD 36
__global__ void k_gemm1(const float* __restrict__ x, const float* __restrict__ W,
                        const float* __restrict__ dis, uint* __restrict__ H1b, int n) {
  __shared__ float xs[128 * GPAD];
  int t = threadIdx.x;
  int r0 = blockIdx.x * 32;
  for (int i = t; i < 32 * 128; i += 256) {
    int rr = i >> 7, kk = i & 127;
    float v = (r0 + rr < n) ? x[(size_t)(r0 + rr) * 128 + kk] : 0.0f;
    xs[kk * GPAD + rr] = v;
  }
  __syncthreads();
  int cg = t & 31;
  int rg = t >> 5;
  float acc[4][4] = {};
#pragma unroll 8
  for (int k = 0; k < 128; ++k) {
    float4 wv = *(const float4*)&W[k * 128 + cg * 4];
    float4 xv = *(const float4*)&xs[k * GPAD + rg * 4];
    acc[0][0] = fmaf(xv.x, wv.x, acc[0][0]);
    acc[0][1] = fmaf(xv.x, wv.y, acc[0][1]);
    acc[0][2] = fmaf(xv.x, wv.z, acc[0][2]);
    acc[0][3] = fmaf(xv.x, wv.w, acc[0][3]);
    acc[1][0] = fmaf(xv.y, wv.x, acc[1][0]);
    acc[1][1] = fmaf(xv.y, wv.y, acc[1][1]);
    acc[1][2] = fmaf(xv.y, wv.z, acc[1][2]);
    acc[1][3] = fmaf(xv.y, wv.w, acc[1][3]);
    acc[2][0] = fmaf(xv.z, wv.x, acc[2][0]);
    acc[2][1] = fmaf(xv.z, wv.y, acc[2][1]);
    acc[2][2] = fmaf(xv.z, wv.z, acc[2][2]);
    acc[2][3] = fmaf(xv.z, wv.w, acc[2][3]);
    acc[3][0] = fmaf(xv.w, wv.x, acc[3][0]);
    acc[3][1] = fmaf(xv.w, wv.y, acc[3][1]);
    acc[3][2] = fmaf(xv.w, wv.z, acc[3][2]);
    acc[3][3] = fmaf(xv.w, wv.w, acc[3][3]);
  }
#pragma unroll
  for (int i = 0; i < 4; ++i) {
    int r = r0 + rg * 4 + i;
    if (r < n) {
      float ds = dis[r];
      uint2 o = {pack2(acc[i][0] * ds, acc[i][1] * ds),
                 pack2(acc[i][2] * ds, acc[i][3] * ds)};
      *(uint2*)&H1b[((uint)r << 6) + cg * 2] = o;
    }
  }
}

// ---- 5. gather1: agg1 = relu(dis_c*(H1s[c] + sum ew*H1s[s]) + b1) ----
// one wave per node; lane owns feature pair (2*lane, 2*lane+1).
__global__ void k_gather1(const int* __restrict__ nbeg, const int* __restrict__ nend,
                          const uint* __restrict__ sed, const uint* __restrict__ H1b,
                          const float* __restrict__ dis, const float* __restrict__ b1,
                          uint* __restrict__ agg1, int n) {
  int w = threadIdx.x >> 6;
  int lane = threadIdx.x & 63;
  int c = blockIdx.x * 4 + w;
  if (c >= n) return;
  uint uc = H1b[((uint)c << 6) | lane];
  float a0 = bflo(uc);
  float a1 = bfhi(uc);
  int j = nbeg[c], j1 = nend[c];
  for (; j + 8 <= j1; j += 8) {           // 8 gathers in flight
    uint r0 = sed[j],     r1 = sed[j + 1], r2 = sed[j + 2], r3 = sed[j + 3];
    uint r4 = sed[j + 4], r5 = sed[j + 5], r6 = sed[j + 6], r7 = sed[j + 7];
    uint u0 = H1b[((r0 >> 16) << 6) | lane];
    uint u1 = H1b[((r1 >> 16) << 6) | lane];
    uint u2 = H1b[((r2 >> 16) << 6) | lane];
    uint u3 = H1b[((r3 >> 16) << 6) | lane];
    uint u4 = H1b[((r4 >> 16) << 6) | lane];
    uint u5 = H1b[((r5 >> 16) << 6) | lane];
    uint u6 = H1b[((r6 >> 16) << 6) | lane];
    uint u7 = H1b[((r7 >> 16) << 6) | lane];
    float w0 = bflo(r0), w1 = bflo(r1), w2 = bflo(r2), w3 = bflo(r3);
    float w4 = bflo(r4), w5 = bflo(r5), w6 = bflo(r6), w7 = bflo(r7);
    a0 = fmaf(w0, bflo(u0), a0); a1 = fmaf(w0, bfhi(u0), a1);
    a0 = fmaf(w1, bflo(u1), a0); a1 = fmaf(w1, bfhi(u1), a1);
    a0 = fmaf(w2, bflo(u2), a0); a1 = fmaf(w2, bfhi(u2), a1);
    a0 = fmaf(w3, bflo(u3), a0); a1 = fmaf(w3, bfhi(u3), a1);
    a0 = fmaf(w4, bflo(u4), a0); a1 = fmaf(w4, bfhi(u4), a1);
    a0 = fmaf(w5, bflo(u5), a0); a1 = fmaf(w5, bfhi(u5), a1);
    a0 = fmaf(w6, bflo(u6), a0); a1 = fmaf(w6, bfhi(u6), a1);
    a0 = fmaf(w7, bflo(u7), a0); a1 = fmaf(w7, bfhi(u7), a1);
  }
  for (; j < j1; ++j) {
    uint r = sed[j];
    uint u = H1b[((r >> 16) << 6) | lane];
    float wv = bflo(r);
    a0 = fmaf(wv, bflo(u), a0);
    a1 = fmaf(wv, bfhi(u), a1);
  }
  float dcs = dis[c];
  float2 bb = *(const float2*)&b1[lane * 2];
  a0 = fmaxf(fmaf(a0, dcs, bb.x), 0.0f);
  a1 = fmaxf(fmaf(a1, dcs, bb.y), 0.0f);
  agg1[((uint)c << 6) | lane] = pack2(a0, a1);
}

// ---- 6. H2s = dis_r * (agg1 @ W2), 64 rows/block, 4x4 reg tile ----
#define G2PAD 68
__global__ void k_gemm2(const uint* __restrict__ agg1, const float* __restrict__ W2,
                        const float* __restrict__ dis, unsigned short* __restrict__ H2b,
                        int n) {
  __shared__ float xs[128 * G2PAD];
  int t = threadIdx.x;
  int r0 = blockIdx.x * 64;
  for (int idx = t; idx < 64 * 64; idx += 256) {
    int row = idx >> 6, i = idx & 63;
    uint u = agg1[((uint)(r0 + row) << 6) | i];
    xs[(2 * i) * G2PAD + row]     = bflo(u);
    xs[(2 * i + 1) * G2PAD + row] = bfhi(u);
  }
  __syncthreads();
  int cg = t & 15;
  int rg = t >> 4;
  float acc[4][4] = {};
#pragma unroll 8
  for (int k = 0; k < 128; ++k) {
    float4 wv = *(const float4*)&W2[k * 64 + cg * 4];
    float4 xv = *(const float4*)&xs[k * G2PAD + rg * 4];
    acc[0][0] = fmaf(xv.x, wv.x, acc[0][0]);
    acc[0][1] = fmaf(xv.x, wv.y, acc[0][1]);
    acc[0][2] = fmaf(xv.x, wv.z, acc[0][2]);
    acc[0][3] = fmaf(xv.x, wv.w, acc[0][3]);
    acc[1][0] = fmaf(xv.y, wv.x, acc[1][0]);
    acc[1][1] = fmaf(xv.y, wv.y, acc[1][1]);
    acc[1][2] = fmaf(xv.y, wv.z, acc[1][2]);
    acc[1][3] = fmaf(xv.y, wv.w, acc[1][3]);
    acc[2][0] = fmaf(xv.z, wv.x, acc[2][0]);
    acc[2][1] = fmaf(xv.z, wv.y, acc[2][1]);
    acc[2][2] = fmaf(xv.z, wv.z, acc[2][2]);
    acc[2][3] = fmaf(xv.z, wv.w, acc[2][3]);
    acc[3][0] = fmaf(xv.w, wv.x, acc[3][0]);
    acc[3][1] = fmaf(xv.w, wv.y, acc[3][1]);
    acc[3][2] = fmaf(xv.w, wv.z, acc[3][2]);
    acc[3][3] = fmaf(xv.w, wv.w, acc[3][3]);
  }
#pragma unroll
  for (int i = 0; i < 4; ++i) {
    int r = r0 + rg * 4 + i;
    if (r < n) {
      float ds = dis[r];
      uint2 o = {pack2(acc[i][0] * ds, acc[i][1] * ds),
                 pack2(acc[i][2] * ds, acc[i][3] * ds)};
      *(uint2*)&H2b[((uint)r << 6) + cg * 4] = o;
    }
  }
}

// ---- 7. gather2 + log_softmax. one wave per node, lane = output col ----
__global__ void k_gather2(const int* __restrict__ nbeg, const int* __restrict__ nend,
                          const uint* __restrict__ sed,
                          const unsigned short* __restrict__ H2b,
                          const float* __restrict__ dis, const float* __restrict__ b2,
                          float* __restrict__ out, int n) {
  int w = threadIdx.x >> 6;
  int lane = threadIdx.x & 63;
  int c = blockIdx.x * 4 + w;
  if (c >= n) return;
  float a = bfs(H2b[((uint)c << 6) | lane]);
  int j = nbeg[c], j1 = nend[c];
  for (; j + 8 <= j1; j += 8) {
    uint r0 = sed[j],     r1 = sed[j + 1], r2 = sed[j + 2], r3 = sed[j + 3];
    uint r4 = sed[j + 4], r5 = sed[j + 5], r6 = sed[j + 6], r7 = sed[j + 7];
    float h0 = bfs(H2b[((r0 >> 16) << 6) | lane]);
    float h1 = bfs(H2b[((r1 >> 16) << 6) | lane]);
    float h2 = bfs(H2b[((r2 >> 16) << 6) | lane]);
    float h3 = bfs(H2b[((r3 >> 16) << 6) | lane]);
    float h4 = bfs(H2b[((r4 >> 16) << 6) | lane]);
    float h5 = bfs(H2b[((r5 >> 16) << 6) | lane]);
    float h6 = bfs(H2b[((r6 >> 16) << 6) | lane]);
    float h7 = bfs(H2b[((r7 >> 16) << 6) | lane]);
    a = fmaf(bflo(r0), h0, a); a = fmaf(bflo(r1), h1, a);
    a = fmaf(bflo(r2), h2, a); a = fmaf(bflo(r3), h3, a);
    a = fmaf(bflo(r4), h4, a); a = fmaf(bflo(r5), h5, a);
    a = fmaf(bflo(r6), h6, a); a = fmaf(bflo(r7), h7, a);
  }
  for (; j < j1; ++j) {
    uint r = sed[j];
    a = fmaf(bflo(r), bfs(H2b[((r >> 16) << 6) | lane]), a);
  }
  a = fmaf(a, dis[c], b2[lane]);
  float m = a;
#pragma unroll
  for (int sft = 32; sft >= 1; sft >>= 1) m = fmaxf(m, __shfl_xor(m, sft, 64));
  float e = expf(a - m);
  float sum = e;
#pragma unroll
  for (int sft = 32; sft >= 1; sft >>= 1) sum += __shfl_xor(sum, sft, 64);
  out[(size_t)c * 64 + lane] = a - m - logf(sum);
}

extern "C" void kernel_launch(void* const* d_in, const int* in_sizes, int n_in,
                              void* d_out, int out_size, void* d_ws, size_t ws_size,
                              hipStream_t stream) {
  const float* x  = (const float*)d_in[0];
  const int*   ei = (const int*)d_in[1];
  const float* ew = (const float*)d_in[2];
  const float* W1 = (const float*)d_in[3];
  const float* b1 = (const float*)d_in[4];
  const float* W2 = (const float*)d_in[5];
  const float* b2 = (const float*)d_in[6];

  const int n = in_sizes[0] / 128;     // 50000
  const int E = in_sizes[1] / 2;       // 800000
  const int* row = ei;
  const int* col = ei + E;
  float* out = (float*)d_out;

  // workspace layout (~41 MB)
  size_t n_r = (size_t)((n + 255) & ~255);    // 50176
  size_t cap = (size_t)NP * CAP_P;            // 950912
  char* ws = (char*)d_ws;
  float* dis  = (float*)ws;            ws += n_r * 4;
  int*   pcur = (int*)ws;              ws += 1024 * 4;
  int*   nbeg = (int*)ws;              ws += n_r * 4;
  int*   nend = (int*)ws;              ws += n_r * 4;
  uint*  rec4 = (uint*)ws;             ws += cap * 4;                 // 3.8 MB
  uint*  sed  = (uint*)ws;             ws += cap * 4;                 // 3.8 MB
  unsigned char* dl8 = (unsigned char*)ws;  ws += (cap + 256) & ~255; // 0.95 MB
  uint*  H1b  = (uint*)ws;             ws += n_r * 64 * 4;            // 12.8 MB
  uint*  agg1 = (uint*)ws;             ws += n_r * 64 * 4;            // 12.8 MB
  unsigned short* H2b = (unsigned short*)ws;                          // 6.4 MB

  const int NB = (E + EPB - 1) / EPB;         // 49

  k_initcur<<<(NP + 255) / 256, 256, 0, stream>>>(pcur);
  k_pscatter<<<NB, 256, 0, stream>>>(row, col, ew, pcur, rec4, dl8, E);
  k_sortdeg<<<NP, 256, 0, stream>>>(pcur, rec4, dl8, sed, nbeg, nend, dis, n);

  k_gemm1<<<(n + 31) / 32, 256, 0, stream>>>(x, W1, dis, H1b, n);
  k_gather1<<<(n + 3) / 4, 256, 0, stream>>>(nbeg, nend, sed, H1b, dis, b1, agg1, n);
  k_gemm2<<<(n + 63) / 64, 256, 0, stream>>>(agg1, W2, dis, H2b, n);
  k_gather2<<<(n + 3) / 4, 256, 0, stream>>>(nbeg, nend, sed, H2b, dis, b2, out, n);
}

// Round 12
// 249.942 us; speedup vs baseline: 5.2770x; 1.1427x over previous
//
#include <hip/hip_runtime.h>

// ---------------------------------------------------------------------------
// GCN 2-layer forward: partitioned low-atomic CSR build + per-node wave gathers.
//   N=50000, E=800000, F: 128 -> 128 -> 64.
//   Partition p owns nodes [p*64, p*64+64), NP=782, CAP_P=1216 slots/partition.
//   Edge record: rec = (src<<16) | bf16(ew).
//   1. initcur: pcur[p] = p*CAP_P
//   2. pscatter: block LDS histogram(782) -> global reserve -> write rec+dl8
//      (EPB=2048 -> 391 blocks: fixes the 49-block grid starvation of r11)
//   3. sortdeg: per-partition counting sort by node -> sed + nbeg/nend + dis
//   4. gemm1:   H1s = dis_r * (x @ W1)    (4x4 reg tile, bf16 store)
//   5. gather1: agg1 = relu(dis_c*(H1s[c] + sum ew*H1s[src]) + b1)   1 wave/node
//   6. gemm2:   H2s = dis_r * (agg1 @ W2) (bf16)
//   7. gather2: out = logsoftmax(dis_c*(H2s[c] + sum ew*H2s[src]) + b2)
// ---------------------------------------------------------------------------

#define NP 782
#define CAP_P 1216
#define EPB 2048

__device__ __forceinline__ float bflo(uint u) { return __uint_as_float(u << 16); }
__device__ __forceinline__ float bfhi(uint u) { return __uint_as_float(u & 0xffff0000u); }
__device__ __forceinline__ float bfs(unsigned short h) { return __uint_as_float(((uint)h) << 16); }
__device__ __forceinline__ unsigned short f2bf(float f) {
  union { float f; uint u; } v{f};
  return (unsigned short)((v.u + 0x7fff + ((v.u >> 16) & 1)) >> 16);  // RNE
}
__device__ __forceinline__ uint pack2(float a, float b) {
  return (uint)f2bf(a) | ((uint)f2bf(b) << 16);
}

__global__ void k_initcur(int* __restrict__ pcur) {
  int i = blockIdx.x * blockDim.x + threadIdx.x;
  if (i < NP) pcur[i] = i * CAP_P;
}

// ---- 2. partition scatter: 2-pass LDS histogram, per-(block,partition) reserve ----
__global__ void k_pscatter(const int* __restrict__ row, const int* __restrict__ col,
                           const float* __restrict__ ew, int* __restrict__ pcur,
                           uint* __restrict__ rec4, unsigned char* __restrict__ dl8,
                           int E) {
  __shared__ int h[NP];
  __shared__ int bse[NP];
  __shared__ int lc[NP];
  int t = threadIdx.x;
  for (int i = t; i < NP; i += 256) h[i] = 0;
  __syncthreads();
  int e0 = blockIdx.x * EPB;
#pragma unroll
  for (int k = 0; k < EPB / 256; ++k) {
    int e = e0 + k * 256 + t;
    if (e < E) atomicAdd(&h[col[e] >> 6], 1);
  }
  __syncthreads();
  for (int i = t; i < NP; i += 256) {
    int c = h[i];
    bse[i] = c ? atomicAdd(&pcur[i], c) : 0;
    lc[i] = 0;
  }
  __syncthreads();
#pragma unroll
  for (int k = 0; k < EPB / 256; ++k) {
    int e = e0 + k * 256 + t;
    if (e < E) {
      int c = col[e];
      int p = c >> 6;
      int s = bse[p] + atomicAdd(&lc[p], 1);
      int lim = (p + 1) * CAP_P - 1;
      s = (s < lim) ? s : lim;               // unreachable for this input
      rec4[s] = ((uint)row[e] << 16) | (uint)f2bf(ew[e]);
      dl8[s] = (unsigned char)(c & 63);
    }
  }
}

// ---- 3. per-partition counting sort by node + degrees ----
__global__ void __launch_bounds__(256) k_sortdeg(
    const int* __restrict__ pcur, const uint* __restrict__ rec4,
    const unsigned char* __restrict__ dl8, uint* __restrict__ sed,
    int* __restrict__ nbeg, int* __restrict__ nend, float* __restrict__ dis, int n) {
  __shared__ int h[64];
  __shared__ int lo[64];
  __shared__ int lc[64];
  __shared__ float sd[64];
  int t = threadIdx.x;
  int p = blockIdx.x;
  if (t < 64) { h[t] = 0; lc[t] = 0; sd[t] = 0.0f; }
  __syncthreads();
  int jb = p * CAP_P;
  int cnt = pcur[p] - jb;
  cnt = (cnt < CAP_P) ? cnt : CAP_P;
  for (int j = t; j < cnt; j += 256) {
    int d = dl8[jb + j];
    atomicAdd(&h[d], 1);
    atomicAdd(&sd[d], bflo(rec4[jb + j]));
  }
  __syncthreads();
  if (t < 64) {
    int v = h[t];
    int x = v;
#pragma unroll
    for (int off = 1; off < 64; off <<= 1) {
      int y = __shfl_up(x, off, 64);
      if (t >= off) x += y;
    }
    int excl = x - v;
    lo[t] = excl;
    int node = p * 64 + t;
    if (node < n) {
      nbeg[node] = jb + excl;
      nend[node] = jb + excl + v;
      dis[node] = rsqrtf(1.0f + sd[t]);
    }
  }
  __syncthreads();
  for (int j = t; j < cnt; j += 256) {
    uint r = rec4[jb + j];
    int d = dl8[jb + j];
    int s = jb + lo[d] + atomicAdd(&lc[d], 1);
    sed[s] = r;
  }
}

// ---- 4. H1s = dis_r * (x @ W1), 32 rows/block, 4x4 reg tile, bf16 out ----
#define GPAD 36
__global__ void k_gemm1(const float* __restrict__ x, const float* __restrict__ W,
                        const float* __restrict__ dis, uint* __restrict__ H1b, int n) {
  __shared__ float xs[128 * GPAD];
  int t = threadIdx.x;
  int r0 = blockIdx.x * 32;
  for (int i = t; i < 32 * 128; i += 256) {
    int rr = i >> 7, kk = i & 127;
    float v = (r0 + rr < n) ? x[(size_t)(r0 + rr) * 128 + kk] : 0.0f;
    xs[kk * GPAD + rr] = v;
  }
  __syncthreads();
  int cg = t & 31;
  int rg = t >> 5;
  float acc[4][4] = {};
#pragma unroll 8
  for (int k = 0; k < 128; ++k) {
    float4 wv = *(const float4*)&W[k * 128 + cg * 4];
    float4 xv = *(const float4*)&xs[k * GPAD + rg * 4];
    acc[0][0] = fmaf(xv.x, wv.x, acc[0][0]);
    acc[0][1] = fmaf(xv.x, wv.y, acc[0][1]);
    acc[0][2] = fmaf(xv.x, wv.z, acc[0][2]);
    acc[0][3] = fmaf(xv.x, wv.w, acc[0][3]);
    acc[1][0] = fmaf(xv.y, wv.x, acc[1][0]);
    acc[1][1] = fmaf(xv.y, wv.y, acc[1][1]);
    acc[1][2] = fmaf(xv.y, wv.z, acc[1][2]);
    acc[1][3] = fmaf(xv.y, wv.w, acc[1][3]);
    acc[2][0] = fmaf(xv.z, wv.x, acc[2][0]);
    acc[2][1] = fmaf(xv.z, wv.y, acc[2][1]);
    acc[2][2] = fmaf(xv.z, wv.z, acc[2][2]);
    acc[2][3] = fmaf(xv.z, wv.w, acc[2][3]);
    acc[3][0] = fmaf(xv.w, wv.x, acc[3][0]);
    acc[3][1] = fmaf(xv.w, wv.y, acc[3][1]);
    acc[3][2] = fmaf(xv.w, wv.z, acc[3][2]);
    acc[3][3] = fmaf(xv.w, wv.w, acc[3][3]);
  }
#pragma unroll
  for (int i = 0; i < 4; ++i) {
    int r = r0 + rg * 4 + i;
    if (r < n) {
      float ds = dis[r];
      uint2 o = {pack2(acc[i][0] * ds, acc[i][1] * ds),
                 pack2(acc[i][2] * ds, acc[i][3] * ds)};
      *(uint2*)&H1b[((uint)r << 6) + cg * 2] = o;
    }
  }
}

// ---- 5. gather1: agg1 = relu(dis_c*(H1s[c] + sum ew*H1s[s]) + b1) ----
// one wave per node; lane owns feature pair (2*lane, 2*lane+1).
__global__ void k_gather1(const int* __restrict__ nbeg, const int* __restrict__ nend,
                          const uint* __restrict__ sed, const uint* __restrict__ H1b,
                          const float* __restrict__ dis, const float* __restrict__ b1,
                          uint* __restrict__ agg1, int n) {
  int w = threadIdx.x >> 6;
  int lane = threadIdx.x & 63;
  int c = blockIdx.x * 4 + w;
  if (c >= n) return;
  uint uc = H1b[((uint)c << 6) | lane];
  float a0 = bflo(uc);
  float a1 = bfhi(uc);
  int j = nbeg[c], j1 = nend[c];
  for (; j + 8 <= j1; j += 8) {           // 8 gathers in flight
    uint r0 = sed[j],     r1 = sed[j + 1], r2 = sed[j + 2], r3 = sed[j + 3];
    uint r4 = sed[j + 4], r5 = sed[j + 5], r6 = sed[j + 6], r7 = sed[j + 7];
    uint u0 = H1b[((r0 >> 16) << 6) | lane];
    uint u1 = H1b[((r1 >> 16) << 6) | lane];
    uint u2 = H1b[((r2 >> 16) << 6) | lane];
    uint u3 = H1b[((r3 >> 16) << 6) | lane];
    uint u4 = H1b[((r4 >> 16) << 6) | lane];
    uint u5 = H1b[((r5 >> 16) << 6) | lane];
    uint u6 = H1b[((r6 >> 16) << 6) | lane];
    uint u7 = H1b[((r7 >> 16) << 6) | lane];
    float w0 = bflo(r0), w1 = bflo(r1), w2 = bflo(r2), w3 = bflo(r3);
    float w4 = bflo(r4), w5 = bflo(r5), w6 = bflo(r6), w7 = bflo(r7);
    a0 = fmaf(w0, bflo(u0), a0); a1 = fmaf(w0, bfhi(u0), a1);
    a0 = fmaf(w1, bflo(u1), a0); a1 = fmaf(w1, bfhi(u1), a1);
    a0 = fmaf(w2, bflo(u2), a0); a1 = fmaf(w2, bfhi(u2), a1);
    a0 = fmaf(w3, bflo(u3), a0); a1 = fmaf(w3, bfhi(u3), a1);
    a0 = fmaf(w4, bflo(u4), a0); a1 = fmaf(w4, bfhi(u4), a1);
    a0 = fmaf(w5, bflo(u5), a0); a1 = fmaf(w5, bfhi(u5), a1);
    a0 = fmaf(w6, bflo(u6), a0); a1 = fmaf(w6, bfhi(u6), a1);
    a0 = fmaf(w7, bflo(u7), a0); a1 = fmaf(w7, bfhi(u7), a1);
  }
  for (; j < j1; ++j) {
    uint r = sed[j];
    uint u = H1b[((r >> 16) << 6) | lane];
    float wv = bflo(r);
    a0 = fmaf(wv, bflo(u), a0);
    a1 = fmaf(wv, bfhi(u), a1);
  }
  float dcs = dis[c];
  float2 bb = *(const float2*)&b1[lane * 2];
  a0 = fmaxf(fmaf(a0, dcs, bb.x), 0.0f);
  a1 = fmaxf(fmaf(a1, dcs, bb.y), 0.0f);
  agg1[((uint)c << 6) | lane] = pack2(a0, a1);
}

// ---- 6. H2s = dis_r * (agg1 @ W2), 64 rows/block, 4x4 reg tile ----
#define G2PAD 68
__global__ void k_gemm2(const uint* __restrict__ agg1, const float* __restrict__ W2,
                        const float* __restrict__ dis, unsigned short* __restrict__ H2b,
                        int n) {
  __shared__ float xs[128 * G2PAD];
  int t = threadIdx.x;
  int r0 = blockIdx.x * 64;
  for (int idx = t; idx < 64 * 64; idx += 256) {
    int row = idx >> 6, i = idx & 63;
    uint u = agg1[((uint)(r0 + row) << 6) | i];
    xs[(2 * i) * G2PAD + row]     = bflo(u);
    xs[(2 * i + 1) * G2PAD + row] = bfhi(u);
  }
  __syncthreads();
  int cg = t & 15;
  int rg = t >> 4;
  float acc[4][4] = {};
#pragma unroll 8
  for (int k = 0; k < 128; ++k) {
    float4 wv = *(const float4*)&W2[k * 64 + cg * 4];
    float4 xv = *(const float4*)&xs[k * G2PAD + rg * 4];
    acc[0][0] = fmaf(xv.x, wv.x, acc[0][0]);
    acc[0][1] = fmaf(xv.x, wv.y, acc[0][1]);
    acc[0][2] = fmaf(xv.x, wv.z, acc[0][2]);
    acc[0][3] = fmaf(xv.x, wv.w, acc[0][3]);
    acc[1][0] = fmaf(xv.y, wv.x, acc[1][0]);
    acc[1][1] = fmaf(xv.y, wv.y, acc[1][1]);
    acc[1][2] = fmaf(xv.y, wv.z, acc[1][2]);
    acc[1][3] = fmaf(xv.y, wv.w, acc[1][3]);
    acc[2][0] = fmaf(xv.z, wv.x, acc[2][0]);
    acc[2][1] = fmaf(xv.z, wv.y, acc[2][1]);
    acc[2][2] = fmaf(xv.z, wv.z, acc[2][2]);
    acc[2][3] = fmaf(xv.z, wv.w, acc[2][3]);
    acc[3][0] = fmaf(xv.w, wv.x, acc[3][0]);
    acc[3][1] = fmaf(xv.w, wv.y, acc[3][1]);
    acc[3][2] = fmaf(xv.w, wv.z, acc[3][2]);
    acc[3][3] = fmaf(xv.w, wv.w, acc[3][3]);
  }
#pragma unroll
  for (int i = 0; i < 4; ++i) {
    int r = r0 + rg * 4 + i;
    if (r < n) {
      float ds = dis[r];
      uint2 o = {pack2(acc[i][0] * ds, acc[i][1] * ds),
                 pack2(acc[i][2] * ds, acc[i][3] * ds)};
      *(uint2*)&H2b[((uint)r << 6) + cg * 4] = o;
    }
  }
}

// ---- 7. gather2 + log_softmax. one wave per node, lane = output col ----
__global__ void k_gather2(const int* __restrict__ nbeg, const int* __restrict__ nend,
                          const uint* __restrict__ sed,
                          const unsigned short* __restrict__ H2b,
                          const float* __restrict__ dis, const float* __restrict__ b2,
                          float* __restrict__ out, int n) {
  int w = threadIdx.x >> 6;
  int lane = threadIdx.x & 63;
  int c = blockIdx.x * 4 + w;
  if (c >= n) return;
  float a = bfs(H2b[((uint)c << 6) | lane]);
  int j = nbeg[c], j1 = nend[c];
  for (; j + 8 <= j1; j += 8) {
    uint r0 = sed[j],     r1 = sed[j + 1], r2 = sed[j + 2], r3 = sed[j + 3];
    uint r4 = sed[j + 4], r5 = sed[j + 5], r6 = sed[j + 6], r7 = sed[j + 7];
    float h0 = bfs(H2b[((r0 >> 16) << 6) | lane]);
    float h1 = bfs(H2b[((r1 >> 16) << 6) | lane]);
    float h2 = bfs(H2b[((r2 >> 16) << 6) | lane]);
    float h3 = bfs(H2b[((r3 >> 16) << 6) | lane]);
    float h4 = bfs(H2b[((r4 >> 16) << 6) | lane]);
    float h5 = bfs(H2b[((r5 >> 16) << 6) | lane]);
    float h6 = bfs(H2b[((r6 >> 16) << 6) | lane]);
    float h7 = bfs(H2b[((r7 >> 16) << 6) | lane]);
    a = fmaf(bflo(r0), h0, a); a = fmaf(bflo(r1), h1, a);
    a = fmaf(bflo(r2), h2, a); a = fmaf(bflo(r3), h3, a);
    a = fmaf(bflo(r4), h4, a); a = fmaf(bflo(r5), h5, a);
    a = fmaf(bflo(r6), h6, a); a = fmaf(bflo(r7), h7, a);
  }
  for (; j < j1; ++j) {
    uint r = sed[j];
    a = fmaf(bflo(r), bfs(H2b[((r >> 16) << 6) | lane]), a);
  }
  a = fmaf(a, dis[c], b2[lane]);
  float m = a;
#pragma unroll
  for (int sft = 32; sft >= 1; sft >>= 1) m = fmaxf(m, __shfl_xor(m, sft, 64));
  float e = expf(a - m);
  float sum = e;
#pragma unroll
  for (int sft = 32; sft >= 1; sft >>= 1) sum += __shfl_xor(sum, sft, 64);
  out[(size_t)c * 64 + lane] = a - m - logf(sum);
}

extern "C" void kernel_launch(void* const* d_in, const int* in_sizes, int n_in,
                              void* d_out, int out_size, void* d_ws, size_t ws_size,
                              hipStream_t stream) {
  const float* x  = (const float*)d_in[0];
  const int*   ei = (const int*)d_in[1];
  const float* ew = (const float*)d_in[2];
  const float* W1 = (const float*)d_in[3];
  const float* b1 = (const float*)d_in[4];
  const float* W2 = (const float*)d_in[5];
  const float* b2 = (const float*)d_in[6];

  const int n = in_sizes[0] / 128;     // 50000
  const int E = in_sizes[1] / 2;       // 800000
  const int* row = ei;
  const int* col = ei + E;
  float* out = (float*)d_out;

  // workspace layout (~41 MB)
  size_t n_r = (size_t)((n + 255) & ~255);    // 50176
  size_t cap = (size_t)NP * CAP_P;            // 950912
  char* ws = (char*)d_ws;
  float* dis  = (float*)ws;            ws += n_r * 4;
  int*   pcur = (int*)ws;              ws += 1024 * 4;
  int*   nbeg = (int*)ws;              ws += n_r * 4;
  int*   nend = (int*)ws;              ws += n_r * 4;
  uint*  rec4 = (uint*)ws;             ws += cap * 4;                 // 3.8 MB
  uint*  sed  = (uint*)ws;             ws += cap * 4;                 // 3.8 MB
  unsigned char* dl8 = (unsigned char*)ws;  ws += (cap + 256) & ~255; // 0.95 MB
  uint*  H1b  = (uint*)ws;             ws += n_r * 64 * 4;            // 12.8 MB
  uint*  agg1 = (uint*)ws;             ws += n_r * 64 * 4;            // 12.8 MB
  unsigned short* H2b = (unsigned short*)ws;                          // 6.4 MB

  const int NB = (E + EPB - 1) / EPB;         // 391

  k_initcur<<<(NP + 255) / 256, 256, 0, stream>>>(pcur);
  k_pscatter<<<NB, 256, 0, stream>>>(row, col, ew, pcur, rec4, dl8, E);
  k_sortdeg<<<NP, 256, 0, stream>>>(pcur, rec4, dl8, sed, nbeg, nend, dis, n);

  k_gemm1<<<(n + 31) / 32, 256, 0, stream>>>(x, W1, dis, H1b, n);
  k_gather1<<<(n + 3) / 4, 256, 0, stream>>>(nbeg, nend, sed, H1b, dis, b1, agg1, n);
  k_gemm2<<<(n + 63) / 64, 256, 0, stream>>>(agg1, W2, dis, H2b, n);
  k_gather2<<<(n + 3) / 4, 256, 0, stream>>>(nbeg, nend, sed, H2b, dis, b2, out, n);
}

// Round 13
// 248.608 us; speedup vs baseline: 5.3053x; 1.0054x over previous
//
#include <hip/hip_runtime.h>

// ---------------------------------------------------------------------------
// GCN 2-layer forward: partitioned low-atomic CSR build + per-node wave gathers.
//   N=50000, E=800000, F: 128 -> 128 -> 64.
//   Partition p owns nodes [p*64, p*64+64), NP=782, CAP_P=1216 slots/partition.
//   Edge record: rec = (src<<16) | bf16(ew).
//   1. initcur: pcur[p] = p*CAP_P
//   2. pscatter: block LDS histogram(782) -> global reserve -> write rec+dl8
//   3. sortdeg: per-partition counting sort by node -> sed + nbeg/nend + dis
//   4. gemm1:   H1s = dis_r * (x @ W1)   64-row blocks, 8x4/thread, PAD-65 LDS
//   5. gather1: agg1 = relu(dis_c*(H1s[c] + sum ew*H1s[src]) + b1)   1 wave/node
//   6. gemm2:   H2s = dis_r * (agg1 @ W2)  bf16-packed LDS
//   7. gather2: out = logsoftmax(dis_c*(H2s[c] + sum ew*H2s[src]) + b2)
// ---------------------------------------------------------------------------

#define NP 782
#define CAP_P 1216
#define EPB 2048

__device__ __forceinline__ float bflo(uint u) { return __uint_as_float(u << 16); }
__device__ __forceinline__ float bfhi(uint u) { return __uint_as_float(u & 0xffff0000u); }
__device__ __forceinline__ float bfs(unsigned short h) { return __uint_as_float(((uint)h) << 16); }
__device__ __forceinline__ unsigned short f2bf(float f) {
  union { float f; uint u; } v{f};
  return (unsigned short)((v.u + 0x7fff + ((v.u >> 16) & 1)) >> 16);  // RNE
}
__device__ __forceinline__ uint pack2(float a, float b) {
  return (uint)f2bf(a) | ((uint)f2bf(b) << 16);
}

__global__ void k_initcur(int* __restrict__ pcur) {
  int i = blockIdx.x * blockDim.x + threadIdx.x;
  if (i < NP) pcur[i] = i * CAP_P;
}

// ---- 2. partition scatter: 2-pass LDS histogram, per-(block,partition) reserve ----
__global__ void k_pscatter(const int* __restrict__ row, const int* __restrict__ col,
                           const float* __restrict__ ew, int* __restrict__ pcur,
                           uint* __restrict__ rec4, unsigned char* __restrict__ dl8,
                           int E) {
  __shared__ int h[NP];
  __shared__ int bse[NP];
  __shared__ int lc[NP];
  int t = threadIdx.x;
  for (int i = t; i < NP; i += 256) h[i] = 0;
  __syncthreads();
  int e0 = blockIdx.x * EPB;
#pragma unroll
  for (int k = 0; k < EPB / 256; ++k) {
    int e = e0 + k * 256 + t;
    if (e < E) atomicAdd(&h[col[e] >> 6], 1);
  }
  __syncthreads();
  for (int i = t; i < NP; i += 256) {
    int c = h[i];
    bse[i] = c ? atomicAdd(&pcur[i], c) : 0;
    lc[i] = 0;
  }
  __syncthreads();
#pragma unroll
  for (int k = 0; k < EPB / 256; ++k) {
    int e = e0 + k * 256 + t;
    if (e < E) {
      int c = col[e];
      int p = c >> 6;
      int s = bse[p] + atomicAdd(&lc[p], 1);
      int lim = (p + 1) * CAP_P - 1;
      s = (s < lim) ? s : lim;               // unreachable for this input
      rec4[s] = ((uint)row[e] << 16) | (uint)f2bf(ew[e]);
      dl8[s] = (unsigned char)(c & 63);
    }
  }
}

// ---- 3. per-partition counting sort by node + degrees ----
__global__ void __launch_bounds__(256) k_sortdeg(
    const int* __restrict__ pcur, const uint* __restrict__ rec4,
    const unsigned char* __restrict__ dl8, uint* __restrict__ sed,
    int* __restrict__ nbeg, int* __restrict__ nend, float* __restrict__ dis, int n) {
  __shared__ int h[64];
  __shared__ int lo[64];
  __shared__ int lc[64];
  __shared__ float sd[64];
  int t = threadIdx.x;
  int p = blockIdx.x;
  if (t < 64) { h[t] = 0; lc[t] = 0; sd[t] = 0.0f; }
  __syncthreads();
  int jb = p * CAP_P;
  int cnt = pcur[p] - jb;
  cnt = (cnt < CAP_P) ? cnt : CAP_P;
  for (int j = t; j < cnt; j += 256) {
    int d = dl8[jb + j];
    atomicAdd(&h[d], 1);
    atomicAdd(&sd[d], bflo(rec4[jb + j]));
  }
  __syncthreads();
  if (t < 64) {
    int v = h[t];
    int x = v;
#pragma unroll
    for (int off = 1; off < 64; off <<= 1) {
      int y = __shfl_up(x, off, 64);
      if (t >= off) x += y;
    }
    int excl = x - v;
    lo[t] = excl;
    int node = p * 64 + t;
    if (node < n) {
      nbeg[node] = jb + excl;
      nend[node] = jb + excl + v;
      dis[node] = rsqrtf(1.0f + sd[t]);
    }
  }
  __syncthreads();
  for (int j = t; j < cnt; j += 256) {
    uint r = rec4[jb + j];
    int d = dl8[jb + j];
    int s = jb + lo[d] + atomicAdd(&lc[d], 1);
    sed[s] = r;
  }
}

// ---- 4. H1s = dis_r * (x @ W1). 64 rows/block, 8 rows x 4 cols per thread.
// LDS transposed [k][row] with PAD=65: conflict-free writes (bank advance 1),
// scalar b32 broadcast reads (8 addrs spaced 8 banks -> 2-way, free).
#define GPAD 65
__global__ void __launch_bounds__(256) k_gemm1(
    const float* __restrict__ x, const float* __restrict__ W,
    const float* __restrict__ dis, uint* __restrict__ H1b, int n) {
  __shared__ float xs[128 * GPAD];    // 33.3 KB
  int t = threadIdx.x;
  int r0 = blockIdx.x * 64;
  for (int i = t; i < 64 * 128; i += 256) {
    int rr = i >> 7, kk = i & 127;
    float v = (r0 + rr < n) ? x[(size_t)(r0 + rr) * 128 + kk] : 0.0f;
    xs[kk * GPAD + rr] = v;
  }
  __syncthreads();
  int cg = t & 31;            // cols 4*cg..4*cg+3
  int rg = t >> 5;            // rows 8*rg..8*rg+7
  float acc[8][4] = {};
#pragma unroll 4
  for (int k = 0; k < 128; ++k) {
    float4 wv = *(const float4*)&W[k * 128 + cg * 4];
    const float* xr = &xs[k * GPAD + rg * 8];
    float xv[8];
#pragma unroll
    for (int j = 0; j < 8; ++j) xv[j] = xr[j];
#pragma unroll
    for (int j = 0; j < 8; ++j) {
      acc[j][0] = fmaf(xv[j], wv.x, acc[j][0]);
      acc[j][1] = fmaf(xv[j], wv.y, acc[j][1]);
      acc[j][2] = fmaf(xv[j], wv.z, acc[j][2]);
      acc[j][3] = fmaf(xv[j], wv.w, acc[j][3]);
    }
  }
#pragma unroll
  for (int j = 0; j < 8; ++j) {
    int r = r0 + rg * 8 + j;
    if (r < n) {
      float ds = dis[r];
      uint2 o = {pack2(acc[j][0] * ds, acc[j][1] * ds),
                 pack2(acc[j][2] * ds, acc[j][3] * ds)};
      *(uint2*)&H1b[((uint)r << 6) + cg * 2] = o;
    }
  }
}

// ---- 5. gather1: agg1 = relu(dis_c*(H1s[c] + sum ew*H1s[s]) + b1) ----
// one wave per node; lane owns feature pair (2*lane, 2*lane+1).
__global__ void k_gather1(const int* __restrict__ nbeg, const int* __restrict__ nend,
                          const uint* __restrict__ sed, const uint* __restrict__ H1b,
                          const float* __restrict__ dis, const float* __restrict__ b1,
                          uint* __restrict__ agg1, int n) {
  int w = threadIdx.x >> 6;
  int lane = threadIdx.x & 63;
  int c = blockIdx.x * 4 + w;
  if (c >= n) return;
  uint uc = H1b[((uint)c << 6) | lane];
  float a0 = bflo(uc);
  float a1 = bfhi(uc);
  int j = nbeg[c], j1 = nend[c];
  for (; j + 8 <= j1; j += 8) {           // 8 gathers in flight
    uint r0 = sed[j],     r1 = sed[j + 1], r2 = sed[j + 2], r3 = sed[j + 3];
    uint r4 = sed[j + 4], r5 = sed[j + 5], r6 = sed[j + 6], r7 = sed[j + 7];
    uint u0 = H1b[((r0 >> 16) << 6) | lane];
    uint u1 = H1b[((r1 >> 16) << 6) | lane];
    uint u2 = H1b[((r2 >> 16) << 6) | lane];
    uint u3 = H1b[((r3 >> 16) << 6) | lane];
    uint u4 = H1b[((r4 >> 16) << 6) | lane];
    uint u5 = H1b[((r5 >> 16) << 6) | lane];
    uint u6 = H1b[((r6 >> 16) << 6) | lane];
    uint u7 = H1b[((r7 >> 16) << 6) | lane];
    float w0 = bflo(r0), w1 = bflo(r1), w2 = bflo(r2), w3 = bflo(r3);
    float w4 = bflo(r4), w5 = bflo(r5), w6 = bflo(r6), w7 = bflo(r7);
    a0 = fmaf(w0, bflo(u0), a0); a1 = fmaf(w0, bfhi(u0), a1);
    a0 = fmaf(w1, bflo(u1), a0); a1 = fmaf(w1, bfhi(u1), a1);
    a0 = fmaf(w2, bflo(u2), a0); a1 = fmaf(w2, bfhi(u2), a1);
    a0 = fmaf(w3, bflo(u3), a0); a1 = fmaf(w3, bfhi(u3), a1);
    a0 = fmaf(w4, bflo(u4), a0); a1 = fmaf(w4, bfhi(u4), a1);
    a0 = fmaf(w5, bflo(u5), a0); a1 = fmaf(w5, bfhi(u5), a1);
    a0 = fmaf(w6, bflo(u6), a0); a1 = fmaf(w6, bfhi(u6), a1);
    a0 = fmaf(w7, bflo(u7), a0); a1 = fmaf(w7, bfhi(u7), a1);
  }
  for (; j < j1; ++j) {
    uint r = sed[j];
    uint u = H1b[((r >> 16) << 6) | lane];
    float wv = bflo(r);
    a0 = fmaf(wv, bflo(u), a0);
    a1 = fmaf(wv, bfhi(u), a1);
  }
  float dcs = dis[c];
  float2 bb = *(const float2*)&b1[lane * 2];
  a0 = fmaxf(fmaf(a0, dcs, bb.x), 0.0f);
  a1 = fmaxf(fmaf(a1, dcs, bb.y), 0.0f);
  agg1[((uint)c << 6) | lane] = pack2(a0, a1);
}

// ---- 6. H2s = dis_r * (agg1 @ W2). 64 rows/block, 4x4/thread.
// LDS holds bf16-packed rows [row][65] (conflict-free writes, broadcast reads).
__global__ void __launch_bounds__(256) k_gemm2(
    const uint* __restrict__ agg1, const float* __restrict__ W2,
    const float* __restrict__ dis, unsigned short* __restrict__ H2b, int n) {
  __shared__ uint xs[64 * 65];        // 16.6 KB
  int t = threadIdx.x;
  int r0 = blockIdx.x * 64;
  for (int idx = t; idx < 64 * 64; idx += 256) {
    int row = idx >> 6, i = idx & 63;
    xs[row * 65 + i] = agg1[((uint)(r0 + row) << 6) | i];
  }
  __syncthreads();
  int cg = t & 15;            // cols 4*cg..4*cg+3
  int rg = t >> 4;            // rows 4*rg..4*rg+3
  float acc[4][4] = {};
#pragma unroll 4
  for (int k2 = 0; k2 < 64; ++k2) {   // k = 2*k2, 2*k2+1
    float4 wv0 = *(const float4*)&W2[(2 * k2) * 64 + cg * 4];
    float4 wv1 = *(const float4*)&W2[(2 * k2 + 1) * 64 + cg * 4];
#pragma unroll
    for (int j = 0; j < 4; ++j) {
      uint u = xs[(rg * 4 + j) * 65 + k2];
      float xlo = bflo(u), xhi = bfhi(u);
      acc[j][0] = fmaf(xlo, wv0.x, acc[j][0]);
      acc[j][1] = fmaf(xlo, wv0.y, acc[j][1]);
      acc[j][2] = fmaf(xlo, wv0.z, acc[j][2]);
      acc[j][3] = fmaf(xlo, wv0.w, acc[j][3]);
      acc[j][0] = fmaf(xhi, wv1.x, acc[j][0]);
      acc[j][1] = fmaf(xhi, wv1.y, acc[j][1]);
      acc[j][2] = fmaf(xhi, wv1.z, acc[j][2]);
      acc[j][3] = fmaf(xhi, wv1.w, acc[j][3]);
    }
  }
#pragma unroll
  for (int j = 0; j < 4; ++j) {
    int r = r0 + rg * 4 + j;
    if (r < n) {
      float ds = dis[r];
      uint2 o = {pack2(acc[j][0] * ds, acc[j][1] * ds),
                 pack2(acc[j][2] * ds, acc[j][3] * ds)};
      *(uint2*)&H2b[((uint)r << 6) + cg * 4] = o;
    }
  }
}

// ---- 7. gather2 + log_softmax. one wave per node, lane = output col ----
__global__ void k_gather2(const int* __restrict__ nbeg, const int* __restrict__ nend,
                          const uint* __restrict__ sed,
                          const unsigned short* __restrict__ H2b,
                          const float* __restrict__ dis, const float* __restrict__ b2,
                          float* __restrict__ out, int n) {
  int w = threadIdx.x >> 6;
  int lane = threadIdx.x & 63;
  int c = blockIdx.x * 4 + w;
  if (c >= n) return;
  float a = bfs(H2b[((uint)c << 6) | lane]);
  int j = nbeg[c], j1 = nend[c];
  for (; j + 8 <= j1; j += 8) {
    uint r0 = sed[j],     r1 = sed[j + 1], r2 = sed[j + 2], r3 = sed[j + 3];
    uint r4 = sed[j + 4], r5 = sed[j + 5], r6 = sed[j + 6], r7 = sed[j + 7];
    float h0 = bfs(H2b[((r0 >> 16) << 6) | lane]);
    float h1 = bfs(H2b[((r1 >> 16) << 6) | lane]);
    float h2 = bfs(H2b[((r2 >> 16) << 6) | lane]);
    float h3 = bfs(H2b[((r3 >> 16) << 6) | lane]);
    float h4 = bfs(H2b[((r4 >> 16) << 6) | lane]);
    float h5 = bfs(H2b[((r5 >> 16) << 6) | lane]);
    float h6 = bfs(H2b[((r6 >> 16) << 6) | lane]);
    float h7 = bfs(H2b[((r7 >> 16) << 6) | lane]);
    a = fmaf(bflo(r0), h0, a); a = fmaf(bflo(r1), h1, a);
    a = fmaf(bflo(r2), h2, a); a = fmaf(bflo(r3), h3, a);
    a = fmaf(bflo(r4), h4, a); a = fmaf(bflo(r5), h5, a);
    a = fmaf(bflo(r6), h6, a); a = fmaf(bflo(r7), h7, a);
  }
  for (; j < j1; ++j) {
    uint r = sed[j];
    a = fmaf(bflo(r), bfs(H2b[((r >> 16) << 6) | lane]), a);
  }
  a = fmaf(a, dis[c], b2[lane]);
  float m = a;
#pragma unroll
  for (int sft = 32; sft >= 1; sft >>= 1) m = fmaxf(m, __shfl_xor(m, sft, 64));
  float e = expf(a - m);
  float sum = e;
#pragma unroll
  for (int sft = 32; sft >= 1; sft >>= 1) sum += __shfl_xor(sum, sft, 64);
  out[(size_t)c * 64 + lane] = a - m - logf(sum);
}

extern "C" void kernel_launch(void* const* d_in, const int* in_sizes, int n_in,
                              void* d_out, int out_size, void* d_ws, size_t ws_size,
                              hipStream_t stream) {
  const float* x  = (const float*)d_in[0];
  const int*   ei = (const int*)d_in[1];
  const float* ew = (const float*)d_in[2];
  const float* W1 = (const float*)d_in[3];
  const float* b1 = (const float*)d_in[4];
  const float* W2 = (const float*)d_in[5];
  const float* b2 = (const float*)d_in[6];

  const int n = in_sizes[0] / 128;     // 50000
  const int E = in_sizes[1] / 2;       // 800000
  const int* row = ei;
  const int* col = ei + E;
  float* out = (float*)d_out;

  // workspace layout (~41 MB)
  size_t n_r = (size_t)((n + 255) & ~255);    // 50176
  size_t cap = (size_t)NP * CAP_P;            // 950912
  char* ws = (char*)d_ws;
  float* dis  = (float*)ws;            ws += n_r * 4;
  int*   pcur = (int*)ws;              ws += 1024 * 4;
  int*   nbeg = (int*)ws;              ws += n_r * 4;
  int*   nend = (int*)ws;              ws += n_r * 4;
  uint*  rec4 = (uint*)ws;             ws += cap * 4;                 // 3.8 MB
  uint*  sed  = (uint*)ws;             ws += cap * 4;                 // 3.8 MB
  unsigned char* dl8 = (unsigned char*)ws;  ws += (cap + 256) & ~255; // 0.95 MB
  uint*  H1b  = (uint*)ws;             ws += n_r * 64 * 4;            // 12.8 MB
  uint*  agg1 = (uint*)ws;             ws += n_r * 64 * 4;            // 12.8 MB
  unsigned short* H2b = (unsigned short*)ws;                          // 6.4 MB

  const int NB = (E + EPB - 1) / EPB;         // 391

  k_initcur<<<(NP + 255) / 256, 256, 0, stream>>>(pcur);
  k_pscatter<<<NB, 256, 0, stream>>>(row, col, ew, pcur, rec4, dl8, E);
  k_sortdeg<<<NP, 256, 0, stream>>>(pcur, rec4, dl8, sed, nbeg, nend, dis, n);

  k_gemm1<<<(n + 63) / 64, 256, 0, stream>>>(x, W1, dis, H1b, n);
  k_gather1<<<(n + 3) / 4, 256, 0, stream>>>(nbeg, nend, sed, H1b, dis, b1, agg1, n);
  k_gemm2<<<(n + 63) / 64, 256, 0, stream>>>(agg1, W2, dis, H2b, n);
  k_gather2<<<(n + 3) / 4, 256, 0, stream>>>(nbeg, nend, sed, H2b, dis, b2, out, n);
}

// Round 14
// 243.503 us; speedup vs baseline: 5.4166x; 1.0210x over previous
//
#include <hip/hip_runtime.h>

// ---------------------------------------------------------------------------
// GCN 2-layer forward: partitioned low-atomic CSR build + per-node wave gathers.
//   N=50000, E=800000, F: 128 -> 128 -> 64.
//   Partition p owns nodes [p*64, p*64+64), NP=782, CAP_P=1216 slots/partition.
//   Edge record: rec = (src<<16) | bf16(ew).
//   1. initcur: pcur[p] = p*CAP_P
//   2. pscatter: block LDS histogram(782) -> global reserve -> write rec+dl8
//   3. sortdeg: per-partition counting sort by node -> sed + nbeg/nend + dis
//   4. gemm1:   H1s = dis_r * (x @ W1)  32 rows/block, row-major LDS, 4x4/thread
//   5. gather1: agg1 = relu(dis_c*(H1s[c] + sum ew*H1s[src]) + b1)   1 wave/node
//   6. gemm2:   H2s = dis_r * (agg1 @ W2)  bf16-packed LDS
//   7. gather2: out = logsoftmax(dis_c*(H2s[c] + sum ew*H2s[src]) + b2)
// ---------------------------------------------------------------------------

#define NP 782
#define CAP_P 1216
#define EPB 2048

__device__ __forceinline__ float bflo(uint u) { return __uint_as_float(u << 16); }
__device__ __forceinline__ float bfhi(uint u) { return __uint_as_float(u & 0xffff0000u); }
__device__ __forceinline__ float bfs(unsigned short h) { return __uint_as_float(((uint)h) << 16); }
__device__ __forceinline__ unsigned short f2bf(float f) {
  union { float f; uint u; } v{f};
  return (unsigned short)((v.u + 0x7fff + ((v.u >> 16) & 1)) >> 16);  // RNE
}
__device__ __forceinline__ uint pack2(float a, float b) {
  return (uint)f2bf(a) | ((uint)f2bf(b) << 16);
}

__global__ void k_initcur(int* __restrict__ pcur) {
  int i = blockIdx.x * blockDim.x + threadIdx.x;
  if (i < NP) pcur[i] = i * CAP_P;
}

// ---- 2. partition scatter: 2-pass LDS histogram, per-(block,partition) reserve ----
__global__ void k_pscatter(const int* __restrict__ row, const int* __restrict__ col,
                           const float* __restrict__ ew, int* __restrict__ pcur,
                           uint* __restrict__ rec4, unsigned char* __restrict__ dl8,
                           int E) {
  __shared__ int h[NP];
  __shared__ int bse[NP];
  __shared__ int lc[NP];
  int t = threadIdx.x;
  for (int i = t; i < NP; i += 256) h[i] = 0;
  __syncthreads();
  int e0 = blockIdx.x * EPB;
#pragma unroll
  for (int k = 0; k < EPB / 256; ++k) {
    int e = e0 + k * 256 + t;
    if (e < E) atomicAdd(&h[col[e] >> 6], 1);
  }
  __syncthreads();
  for (int i = t; i < NP; i += 256) {
    int c = h[i];
    bse[i] = c ? atomicAdd(&pcur[i], c) : 0;
    lc[i] = 0;
  }
  __syncthreads();
#pragma unroll
  for (int k = 0; k < EPB / 256; ++k) {
    int e = e0 + k * 256 + t;
    if (e < E) {
      int c = col[e];
      int p = c >> 6;
      int s = bse[p] + atomicAdd(&lc[p], 1);
      int lim = (p + 1) * CAP_P - 1;
      s = (s < lim) ? s : lim;               // unreachable for this input
      rec4[s] = ((uint)row[e] << 16) | (uint)f2bf(ew[e]);
      dl8[s] = (unsigned char)(c & 63);
    }
  }
}

// ---- 3. per-partition counting sort by node + degrees ----
__global__ void __launch_bounds__(256) k_sortdeg(
    const int* __restrict__ pcur, const uint* __restrict__ rec4,
    const unsigned char* __restrict__ dl8, uint* __restrict__ sed,
    int* __restrict__ nbeg, int* __restrict__ nend, float* __restrict__ dis, int n) {
  __shared__ int h[64];
  __shared__ int lo[64];
  __shared__ int lc[64];
  __shared__ float sd[64];
  int t = threadIdx.x;
  int p = blockIdx.x;
  if (t < 64) { h[t] = 0; lc[t] = 0; sd[t] = 0.0f; }
  __syncthreads();
  int jb = p * CAP_P;
  int cnt = pcur[p] - jb;
  cnt = (cnt < CAP_P) ? cnt : CAP_P;
  for (int j = t; j < cnt; j += 256) {
    int d = dl8[jb + j];
    atomicAdd(&h[d], 1);
    atomicAdd(&sd[d], bflo(rec4[jb + j]));
  }
  __syncthreads();
  if (t < 64) {
    int v = h[t];
    int x = v;
#pragma unroll
    for (int off = 1; off < 64; off <<= 1) {
      int y = __shfl_up(x, off, 64);
      if (t >= off) x += y;
    }
    int excl = x - v;
    lo[t] = excl;
    int node = p * 64 + t;
    if (node < n) {
      nbeg[node] = jb + excl;
      nend[node] = jb + excl + v;
      dis[node] = rsqrtf(1.0f + sd[t]);
    }
  }
  __syncthreads();
  for (int j = t; j < cnt; j += 256) {
    uint r = rec4[jb + j];
    int d = dl8[jb + j];
    int s = jb + lo[d] + atomicAdd(&lc[d], 1);
    sed[s] = r;
  }
}

// ---- 4. H1s = dis_r * (x @ W1). 32 rows/block, 4 rows x 4 cols per thread.
// x row-major in LDS [32][132]: float4 staging, scalar broadcast reads.
#define PADK 132
__global__ void __launch_bounds__(256) k_gemm1(
    const float* __restrict__ x, const float* __restrict__ W,
    const float* __restrict__ dis, uint* __restrict__ H1b, int n) {
  __shared__ float xs[32 * PADK];     // 16.9 KB
  int t = threadIdx.x;
  int r0 = blockIdx.x * 32;
  for (int i = t; i < 32 * 32; i += 256) {
    int rr = i >> 5, c4 = (i & 31) * 4;
    int r = r0 + rr;
    float4 v = {0.0f, 0.0f, 0.0f, 0.0f};
    if (r < n) v = *(const float4*)&x[(size_t)r * 128 + c4];
    *(float4*)&xs[rr * PADK + c4] = v;
  }
  __syncthreads();
  int cg = t & 31;            // cols 4*cg..4*cg+3
  int rg = t >> 5;            // rows 4*rg..4*rg+3
  const float* xr0 = &xs[(rg * 4 + 0) * PADK];
  const float* xr1 = &xs[(rg * 4 + 1) * PADK];
  const float* xr2 = &xs[(rg * 4 + 2) * PADK];
  const float* xr3 = &xs[(rg * 4 + 3) * PADK];
  float acc[4][4] = {};
#pragma unroll 4
  for (int k = 0; k < 128; ++k) {
    float4 wv = *(const float4*)&W[k * 128 + cg * 4];
    float x0 = xr0[k], x1 = xr1[k], x2 = xr2[k], x3 = xr3[k];
    acc[0][0] = fmaf(x0, wv.x, acc[0][0]);
    acc[0][1] = fmaf(x0, wv.y, acc[0][1]);
    acc[0][2] = fmaf(x0, wv.z, acc[0][2]);
    acc[0][3] = fmaf(x0, wv.w, acc[0][3]);
    acc[1][0] = fmaf(x1, wv.x, acc[1][0]);
    acc[1][1] = fmaf(x1, wv.y, acc[1][1]);
    acc[1][2] = fmaf(x1, wv.z, acc[1][2]);
    acc[1][3] = fmaf(x1, wv.w, acc[1][3]);
    acc[2][0] = fmaf(x2, wv.x, acc[2][0]);
    acc[2][1] = fmaf(x2, wv.y, acc[2][1]);
    acc[2][2] = fmaf(x2, wv.z, acc[2][2]);
    acc[2][3] = fmaf(x2, wv.w, acc[2][3]);
    acc[3][0] = fmaf(x3, wv.x, acc[3][0]);
    acc[3][1] = fmaf(x3, wv.y, acc[3][1]);
    acc[3][2] = fmaf(x3, wv.z, acc[3][2]);
    acc[3][3] = fmaf(x3, wv.w, acc[3][3]);
  }
#pragma unroll
  for (int j = 0; j < 4; ++j) {
    int r = r0 + rg * 4 + j;
    if (r < n) {
      float ds = dis[r];
      uint2 o = {pack2(acc[j][0] * ds, acc[j][1] * ds),
                 pack2(acc[j][2] * ds, acc[j][3] * ds)};
      *(uint2*)&H1b[((uint)r << 6) + cg * 2] = o;
    }
  }
}

// ---- 5. gather1: agg1 = relu(dis_c*(H1s[c] + sum ew*H1s[s]) + b1) ----
// one wave per node; lane owns feature pair (2*lane, 2*lane+1).
__global__ void k_gather1(const int* __restrict__ nbeg, const int* __restrict__ nend,
                          const uint* __restrict__ sed, const uint* __restrict__ H1b,
                          const float* __restrict__ dis, const float* __restrict__ b1,
                          uint* __restrict__ agg1, int n) {
  int w = threadIdx.x >> 6;
  int lane = threadIdx.x & 63;
  int c = blockIdx.x * 4 + w;
  if (c >= n) return;
  uint uc = H1b[((uint)c << 6) | lane];
  float a0 = bflo(uc);
  float a1 = bfhi(uc);
  int j = nbeg[c], j1 = nend[c];
  for (; j + 8 <= j1; j += 8) {           // 8 gathers in flight
    uint r0 = sed[j],     r1 = sed[j + 1], r2 = sed[j + 2], r3 = sed[j + 3];
    uint r4 = sed[j + 4], r5 = sed[j + 5], r6 = sed[j + 6], r7 = sed[j + 7];
    uint u0 = H1b[((r0 >> 16) << 6) | lane];
    uint u1 = H1b[((r1 >> 16) << 6) | lane];
    uint u2 = H1b[((r2 >> 16) << 6) | lane];
    uint u3 = H1b[((r3 >> 16) << 6) | lane];
    uint u4 = H1b[((r4 >> 16) << 6) | lane];
    uint u5 = H1b[((r5 >> 16) << 6) | lane];
    uint u6 = H1b[((r6 >> 16) << 6) | lane];
    uint u7 = H1b[((r7 >> 16) << 6) | lane];
    float w0 = bflo(r0), w1 = bflo(r1), w2 = bflo(r2), w3 = bflo(r3);
    float w4 = bflo(r4), w5 = bflo(r5), w6 = bflo(r6), w7 = bflo(r7);
    a0 = fmaf(w0, bflo(u0), a0); a1 = fmaf(w0, bfhi(u0), a1);
    a0 = fmaf(w1, bflo(u1), a0); a1 = fmaf(w1, bfhi(u1), a1);
    a0 = fmaf(w2, bflo(u2), a0); a1 = fmaf(w2, bfhi(u2), a1);
    a0 = fmaf(w3, bflo(u3), a0); a1 = fmaf(w3, bfhi(u3), a1);
    a0 = fmaf(w4, bflo(u4), a0); a1 = fmaf(w4, bfhi(u4), a1);
    a0 = fmaf(w5, bflo(u5), a0); a1 = fmaf(w5, bfhi(u5), a1);
    a0 = fmaf(w6, bflo(u6), a0); a1 = fmaf(w6, bfhi(u6), a1);
    a0 = fmaf(w7, bflo(u7), a0); a1 = fmaf(w7, bfhi(u7), a1);
  }
  for (; j < j1; ++j) {
    uint r = sed[j];
    uint u = H1b[((r >> 16) << 6) | lane];
    float wv = bflo(r);
    a0 = fmaf(wv, bflo(u), a0);
    a1 = fmaf(wv, bfhi(u), a1);
  }
  float dcs = dis[c];
  float2 bb = *(const float2*)&b1[lane * 2];
  a0 = fmaxf(fmaf(a0, dcs, bb.x), 0.0f);
  a1 = fmaxf(fmaf(a1, dcs, bb.y), 0.0f);
  agg1[((uint)c << 6) | lane] = pack2(a0, a1);
}

// ---- 6. H2s = dis_r * (agg1 @ W2). 64 rows/block, 4x4/thread.
// LDS holds bf16-packed rows [row][65] (conflict-free writes, broadcast reads).
__global__ void __launch_bounds__(256) k_gemm2(
    const uint* __restrict__ agg1, const float* __restrict__ W2,
    const float* __restrict__ dis, unsigned short* __restrict__ H2b, int n) {
  __shared__ uint xs[64 * 65];        // 16.6 KB
  int t = threadIdx.x;
  int r0 = blockIdx.x * 64;
  for (int idx = t; idx < 64 * 64; idx += 256) {
    int row = idx >> 6, i = idx & 63;
    xs[row * 65 + i] = agg1[((uint)(r0 + row) << 6) | i];
  }
  __syncthreads();
  int cg = t & 15;            // cols 4*cg..4*cg+3
  int rg = t >> 4;            // rows 4*rg..4*rg+3
  float acc[4][4] = {};
#pragma unroll 4
  for (int k2 = 0; k2 < 64; ++k2) {   // k = 2*k2, 2*k2+1
    float4 wv0 = *(const float4*)&W2[(2 * k2) * 64 + cg * 4];
    float4 wv1 = *(const float4*)&W2[(2 * k2 + 1) * 64 + cg * 4];
#pragma unroll
    for (int j = 0; j < 4; ++j) {
      uint u = xs[(rg * 4 + j) * 65 + k2];
      float xlo = bflo(u), xhi = bfhi(u);
      acc[j][0] = fmaf(xlo, wv0.x, acc[j][0]);
      acc[j][1] = fmaf(xlo, wv0.y, acc[j][1]);
      acc[j][2] = fmaf(xlo, wv0.z, acc[j][2]);
      acc[j][3] = fmaf(xlo, wv0.w, acc[j][3]);
      acc[j][0] = fmaf(xhi, wv1.x, acc[j][0]);
      acc[j][1] = fmaf(xhi, wv1.y, acc[j][1]);
      acc[j][2] = fmaf(xhi, wv1.z, acc[j][2]);
      acc[j][3] = fmaf(xhi, wv1.w, acc[j][3]);
    }
  }
#pragma unroll
  for (int j = 0; j < 4; ++j) {
    int r = r0 + rg * 4 + j;
    if (r < n) {
      float ds = dis[r];
      uint2 o = {pack2(acc[j][0] * ds, acc[j][1] * ds),
                 pack2(acc[j][2] * ds, acc[j][3] * ds)};
      *(uint2*)&H2b[((uint)r << 6) + cg * 4] = o;
    }
  }
}

// ---- 7. gather2 + log_softmax. one wave per node, lane = output col ----
__global__ void k_gather2(const int* __restrict__ nbeg, const int* __restrict__ nend,
                          const uint* __restrict__ sed,
                          const unsigned short* __restrict__ H2b,
                          const float* __restrict__ dis, const float* __restrict__ b2,
                          float* __restrict__ out, int n) {
  int w = threadIdx.x >> 6;
  int lane = threadIdx.x & 63;
  int c = blockIdx.x * 4 + w;
  if (c >= n) return;
  float a = bfs(H2b[((uint)c << 6) | lane]);
  int j = nbeg[c], j1 = nend[c];
  for (; j + 8 <= j1; j += 8) {
    uint r0 = sed[j],     r1 = sed[j + 1], r2 = sed[j + 2], r3 = sed[j + 3];
    uint r4 = sed[j + 4], r5 = sed[j + 5], r6 = sed[j + 6], r7 = sed[j + 7];
    float h0 = bfs(H2b[((r0 >> 16) << 6) | lane]);
    float h1 = bfs(H2b[((r1 >> 16) << 6) | lane]);
    float h2 = bfs(H2b[((r2 >> 16) << 6) | lane]);
    float h3 = bfs(H2b[((r3 >> 16) << 6) | lane]);
    float h4 = bfs(H2b[((r4 >> 16) << 6) | lane]);
    float h5 = bfs(H2b[((r5 >> 16) << 6) | lane]);
    float h6 = bfs(H2b[((r6 >> 16) << 6) | lane]);
    float h7 = bfs(H2b[((r7 >> 16) << 6) | lane]);
    a = fmaf(bflo(r0), h0, a); a = fmaf(bflo(r1), h1, a);
    a = fmaf(bflo(r2), h2, a); a = fmaf(bflo(r3), h3, a);
    a = fmaf(bflo(r4), h4, a); a = fmaf(bflo(r5), h5, a);
    a = fmaf(bflo(r6), h6, a); a = fmaf(bflo(r7), h7, a);
  }
  for (; j < j1; ++j) {
    uint r = sed[j];
    a = fmaf(bflo(r), bfs(H2b[((r >> 16) << 6) | lane]), a);
  }
  a = fmaf(a, dis[c], b2[lane]);
  float m = a;
#pragma unroll
  for (int sft = 32; sft >= 1; sft >>= 1) m = fmaxf(m, __shfl_xor(m, sft, 64));
  float e = expf(a - m);
  float sum = e;
#pragma unroll
  for (int sft = 32; sft >= 1; sft >>= 1) sum += __shfl_xor(sum, sft, 64);
  out[(size_t)c * 64 + lane] = a - m - logf(sum);
}

extern "C" void kernel_launch(void* const* d_in, const int* in_sizes, int n_in,
                              void* d_out, int out_size, void* d_ws, size_t ws_size,
                              hipStream_t stream) {
  const float* x  = (const float*)d_in[0];
  const int*   ei = (const int*)d_in[1];
  const float* ew = (const float*)d_in[2];
  const float* W1 = (const float*)d_in[3];
  const float* b1 = (const float*)d_in[4];
  const float* W2 = (const float*)d_in[5];
  const float* b2 = (const float*)d_in[6];

  const int n = in_sizes[0] / 128;     // 50000
  const int E = in_sizes[1] / 2;       // 800000
  const int* row = ei;
  const int* col = ei + E;
  float* out = (float*)d_out;

  // workspace layout (~41 MB)
  size_t n_r = (size_t)((n + 255) & ~255);    // 50176
  size_t cap = (size_t)NP * CAP_P;            // 950912
  char* ws = (char*)d_ws;
  float* dis  = (float*)ws;            ws += n_r * 4;
  int*   pcur = (int*)ws;              ws += 1024 * 4;
  int*   nbeg = (int*)ws;              ws += n_r * 4;
  int*   nend = (int*)ws;              ws += n_r * 4;
  uint*  rec4 = (uint*)ws;             ws += cap * 4;                 // 3.8 MB
  uint*  sed  = (uint*)ws;             ws += cap * 4;                 // 3.8 MB
  unsigned char* dl8 = (unsigned char*)ws;  ws += (cap + 256) & ~255; // 0.95 MB
  uint*  H1b  = (uint*)ws;             ws += n_r * 64 * 4;            // 12.8 MB
  uint*  agg1 = (uint*)ws;             ws += n_r * 64 * 4;            // 12.8 MB
  unsigned short* H2b = (unsigned short*)ws;                          // 6.4 MB

  const int NB = (E + EPB - 1) / EPB;         // 391

  k_initcur<<<(NP + 255) / 256, 256, 0, stream>>>(pcur);
  k_pscatter<<<NB, 256, 0, stream>>>(row, col, ew, pcur, rec4, dl8, E);
  k_sortdeg<<<NP, 256, 0, stream>>>(pcur, rec4, dl8, sed, nbeg, nend, dis, n);

  k_gemm1<<<(n + 31) / 32, 256, 0, stream>>>(x, W1, dis, H1b, n);
  k_gather1<<<(n + 3) / 4, 256, 0, stream>>>(nbeg, nend, sed, H1b, dis, b1, agg1, n);
  k_gemm2<<<(n + 63) / 64, 256, 0, stream>>>(agg1, W2, dis, H2b, n);
  k_gather2<<<(n + 3) / 4, 256, 0, stream>>>(nbeg, nend, sed, H2b, dis, b2, out, n);
}